// Round 15
// baseline (277.860 us; speedup 1.0000x reference)
//
#include <hip/hip_runtime.h>
#include <cstddef>
#include <cstdint>

#define SEQ    2048
#define DMODEL 1024
#define NHEAD  16
#define HDIM   64
#define SCALE  0.125f
#define LOG2E  1.4426950408889634f

typedef _Float16 f16;
typedef unsigned short u16;
typedef unsigned int   u32;
typedef __attribute__((ext_vector_type(8))) _Float16 h8v;
typedef __attribute__((ext_vector_type(4))) _Float16 h4v;
typedef __attribute__((ext_vector_type(4))) float    f4v;

__device__ __forceinline__ u32 pkh(float a, float b) {
    u16 x = __builtin_bit_cast(u16, (f16)a);
    u16 y = __builtin_bit_cast(u16, (f16)b);
    return (u32)x | ((u32)y << 16);
}

__device__ __forceinline__ float fexp2(float x) {
#if __has_builtin(__builtin_amdgcn_exp2f)
    return __builtin_amdgcn_exp2f(x);
#else
    return exp2f(x);
#endif
}

__device__ __forceinline__ f4v mfma32(h8v a, h8v b, f4v c) {
    return __builtin_amdgcn_mfma_f32_16x16x32_f16(a, b, c, 0, 0, 0);
}
__device__ __forceinline__ f4v mfma16(h4v a, h4v b, f4v c) {
    return __builtin_amdgcn_mfma_f32_16x16x16f16(a, b, c, 0, 0, 0);
}

// async global->LDS, 16B per lane; dst is wave-uniform base + lane*16
#define GLD16(src, dst) __builtin_amdgcn_global_load_lds(                    \
        (const __attribute__((address_space(1))) void*)(src),                \
        (__attribute__((address_space(3))) void*)(dst), 16, 0, 0)

// ---------------------------------------------------------------------------
// RoPE table: tab[pos*32+t] = (cos, sin) of pos / 10000^(2t/64).
// ---------------------------------------------------------------------------
__global__ __launch_bounds__(256)
void rope_tab_kernel(float2* __restrict__ tab)
{
    int gid = blockIdx.x * 256 + threadIdx.x;   // 65536
    int pos = gid >> 5, t = gid & 31;
    float inv = exp2f((float)(-2 * t) * (0.015625f * 13.287712379549449f));
    float c, s;
    sincosf((float)pos * inv, &s, &c);
    tab[gid] = make_float2(c, s);
}

// ---------------------------------------------------------------------------
// Convert x, Wqkv, Wout (fp32) -> f16 row-major copies.
// ---------------------------------------------------------------------------
__global__ __launch_bounds__(256)
void cvt_f16_kernel(const float* __restrict__ x, const float* __restrict__ Wqkv,
                    const float* __restrict__ Wout,
                    f16* __restrict__ Xh, f16* __restrict__ Wqh, f16* __restrict__ Woh)
{
    size_t i = ((size_t)blockIdx.x * 256 + threadIdx.x) * 8;
    const float* src; f16* dst; size_t off;
    if (i < 4194304)      { src = x;    dst = Xh;  off = i; }
    else if (i < 7340032) { src = Wqkv; dst = Wqh; off = i - 4194304; }
    else                  { src = Wout; dst = Woh; off = i - 7340032; }
    float4 a = *(const float4*)&src[off];
    float4 b = *(const float4*)&src[off + 4];
    uint4 o;
    o.x = pkh(a.x, a.y); o.y = pkh(a.z, a.w);
    o.z = pkh(b.x, b.y); o.w = pkh(b.z, b.w);
    *(uint4*)&dst[off] = o;
}

// ---------------------------------------------------------------------------
// f16 MFMA GEMM: C = A @ B^T + bias. 128x128 tile, BK=32, 4 waves.
// Staging via global_load_lds width=16: LINEAR LDS dest (slot s at byte s*16,
// s = row*4 + sw), INVERSE-swizzled global source (slot sw holds kslot
// sw^(row&3)), swizzled read unchanged (reads sw = lc^(row&3) -> kslot lc).
// mode 0: store f16. mode 1: store fp32.
// ---------------------------------------------------------------------------
__global__ __launch_bounds__(256)
void gemm_f16_kernel(const f16* __restrict__ A, const f16* __restrict__ B,
                     const float* __restrict__ bias, void* __restrict__ Cout,
                     int N, int K, int mode)
{
    __shared__ __align__(16) char Asb[8192];
    __shared__ __align__(16) char Bsb[8192];
    int tid = threadIdx.x;
    int w = tid >> 6, l = tid & 63, lr = l & 15, lc = l >> 4;
    int row0 = blockIdx.y * 128, col0 = blockIdx.x * 128;
    int wr = (w >> 1) * 64, wc = (w & 1) * 64;

    f4v acc[4][4];
    #pragma unroll
    for (int m = 0; m < 4; ++m)
        #pragma unroll
        for (int n = 0; n < 4; ++n) acc[m][n] = (f4v){0.f, 0.f, 0.f, 0.f};

    // slot s=tid and s=tid+256; row = s>>2, sw = s&3 = tid&3, ksrc = sw^(row&3)
    int r0 = tid >> 2;
    int k0 = (tid & 3) ^ (r0 & 3);
    int r1 = (tid + 256) >> 2;
    int k1 = (tid & 3) ^ (r1 & 3);
    char* lA0 = Asb + w * 1024;          // wave-uniform chunk bases
    char* lA1 = Asb + 4096 + w * 1024;
    char* lB0 = Bsb + w * 1024;
    char* lB1 = Bsb + 4096 + w * 1024;

    const f16* pa0 = &A[(size_t)(row0 + r0) * K + k0 * 8];
    const f16* pa1 = &A[(size_t)(row0 + r1) * K + k1 * 8];
    const f16* pb0 = &B[(size_t)(col0 + r0) * K + k0 * 8];
    const f16* pb1 = &B[(size_t)(col0 + r1) * K + k1 * 8];

    GLD16(pa0, lA0); GLD16(pa1, lA1);
    GLD16(pb0, lB0); GLD16(pb1, lB1);

    int NT = K >> 5;
    for (int kt = 0; kt < NT; ++kt) {
        __syncthreads();   // drains vmcnt -> staged tile ready
        h8v af[4], bf[4];
        #pragma unroll
        for (int m = 0; m < 4; ++m) {
            int row = wr + m * 16 + lr;
            af[m] = *(h8v*)(Asb + row * 64 + ((lc ^ (row & 3)) << 4));
        }
        #pragma unroll
        for (int n = 0; n < 4; ++n) {
            int col = wc + n * 16 + lr;
            bf[n] = *(h8v*)(Bsb + col * 64 + ((lc ^ (col & 3)) << 4));
        }
        #pragma unroll
        for (int m = 0; m < 4; ++m)
            #pragma unroll
            for (int n = 0; n < 4; ++n)
                acc[m][n] = mfma32(af[m], bf[n], acc[m][n]);
        __syncthreads();   // all reads done before overwrite
        if (kt + 1 < NT) {
            int kk = (kt + 1) * 32;
            GLD16(pa0 + kk, lA0); GLD16(pa1 + kk, lA1);
            GLD16(pb0 + kk, lB0); GLD16(pb1 + kk, lB1);
        }
    }

    #pragma unroll
    for (int m = 0; m < 4; ++m)
        #pragma unroll
        for (int r = 0; r < 4; ++r) {
            int row = row0 + wr + m * 16 + lc * 4 + r;
            #pragma unroll
            for (int n = 0; n < 4; ++n) {
                int col = col0 + wc + n * 16 + lr;
                float v = acc[m][n][r] + bias[col];
                if (mode == 0) ((f16*)Cout)[(size_t)row * N + col] = (f16)v;
                else           ((float*)Cout)[(size_t)row * N + col] = v;
            }
        }
}

// ---------------------------------------------------------------------------
// Pack Q,K (RoPE via table) from f16 QKV [row][3072] into f16 MFMA frag layout.
// ---------------------------------------------------------------------------
__global__ __launch_bounds__(256)
void pack_qk_kernel(const f16* __restrict__ QKVh, const float2* __restrict__ tab,
                    f16* __restrict__ Qh, f16* __restrict__ Kh)
{
    int gid = blockIdx.x * 256 + threadIdx.x;
    int i     = gid & 15;
    int t8    = (gid >> 4) & 3;
    int h     = (gid >> 6) & 15;
    int rh    = (gid >> 10) & 255;
    int which = (gid >> 18) & 1;
    int row = rh * 16 + i;
    int pos = row & (SEQ - 1);
    int b   = row >> 11;
    f16* dst = which ? Kh : Qh;

    h8v x1 = *(const h8v*)&QKVh[(size_t)row * 3072 + which * 1024 + h * 64 + t8 * 8];
    h8v x2 = *(const h8v*)&QKVh[(size_t)row * 3072 + which * 1024 + h * 64 + t8 * 8 + 32];

    float y1[8], y2[8];
    #pragma unroll
    for (int e = 0; e < 8; ++e) {
        int t = t8 * 8 + e;
        float2 cs = tab[pos * 32 + t];
        float a1 = (float)x1[e], a2 = (float)x2[e];
        y1[e] = a1 * cs.x - a2 * cs.y;
        y2[e] = a1 * cs.y + a2 * cs.x;
    }
    int it = pos >> 4;
    size_t b0 = (((((size_t)(b*128 + it)*16 + h)*2 + 0)*4 + t8)*16 + i)*8;
    size_t b1 = (((((size_t)(b*128 + it)*16 + h)*2 + 1)*4 + t8)*16 + i)*8;
    uint4 o0, o1;
    o0.x = pkh(y1[0], y1[1]); o0.y = pkh(y1[2], y1[3]);
    o0.z = pkh(y1[4], y1[5]); o0.w = pkh(y1[6], y1[7]);
    o1.x = pkh(y2[0], y2[1]); o1.y = pkh(y2[2], y2[3]);
    o1.z = pkh(y2[4], y2[5]); o1.w = pkh(y2[6], y2[7]);
    *(uint4*)(dst + b0) = o0;
    *(uint4*)(dst + b1) = o1;
}

// ---------------------------------------------------------------------------
// Pack V from f16 QKV [row][3072] (cols 2048..3071) into PV B-frag layout.
// ---------------------------------------------------------------------------
__global__ __launch_bounds__(256)
void pack_v_kernel(const f16* __restrict__ QKVh, f16* __restrict__ Vt)
{
    int gid = blockIdx.x * 256 + threadIdx.x;
    int dd = gid & 15;
    int jc = (gid >> 4) & 3;
    int dt = (gid >> 6) & 3;
    int g  = (gid >> 8) & 15;
    int jt = (gid >> 12) & 63;
    int b  = (gid >> 18) & 1;
    int d = g * 64 + dt * 16 + dd;
    f16 v[8];
    #pragma unroll
    for (int e = 0; e < 8; ++e) {
        int j = jt * 32 + jc * 8 + e;
        v[e] = QKVh[(size_t)(b * SEQ + j) * 3072 + 2048 + d];
    }
    size_t off = ((((((size_t)b*64 + jt)*16 + g)*4 + dt)*4 + jc)*16 + dd)*8;
    uint4 o;
    o.x = pkh((float)v[0], (float)v[1]); o.y = pkh((float)v[2], (float)v[3]);
    o.z = pkh((float)v[4], (float)v[5]); o.w = pkh((float)v[6], (float)v[7]);
    *(uint4*)(Vt + off) = o;
}

// ---------------------------------------------------------------------------
// Sum 2 f16 attention split partials -> f16 CTX [4096][1024]. Grid 2048.
// ---------------------------------------------------------------------------
__global__ __launch_bounds__(256)
void pack_ctx_kernel(const f16* __restrict__ Cp, f16* __restrict__ Ch)
{
    size_t i = ((size_t)blockIdx.x * 256 + threadIdx.x) * 8;
    h8v p0 = *(const h8v*)&Cp[i];
    h8v p1 = *(const h8v*)&Cp[i + 4194304];
    float s[8];
    #pragma unroll
    for (int e = 0; e < 8; ++e)
        s[e] = (float)p0[e] + (float)p1[e];
    uint4 o;
    o.x = pkh(s[0], s[1]); o.y = pkh(s[2], s[3]);
    o.z = pkh(s[4], s[5]); o.w = pkh(s[6], s[7]);
    *(uint4*)&Ch[i] = o;
}

// ---------------------------------------------------------------------------
// Two-pass MFMA talking-heads attention. 1024 threads = 16 waves, 1 head/wave.
// QBLK=32, j-step=64.
// FULL=0: 4 splits of 512 (grid 512, 2 blocks/CU, LDS 64KB) -> Z partials.
// FULL=1: 2 splits of 1024 (grid 256, LDS 131KB) -> CTX partials;
//         log2(Z) folded into premix MFMA C-operand; K burst-0 register
//         prefetch across steps (lands during premix+PV of previous step).
// bid=(split*2+b)*64+it2 (chunked XCD locality).
// ---------------------------------------------------------------------------
template<int FULL>
__global__ __launch_bounds__(1024, FULL ? 1 : 2)
void attn_core(const f16* __restrict__ Qh, const f16* __restrict__ Kh,
               const f16* __restrict__ Vt, const float* __restrict__ Wpre,
               const float* __restrict__ Wpost, const float* __restrict__ Zp,
               float* __restrict__ Zout, f16* __restrict__ Octx)
{
    __shared__ __align__(16) char ss[65536];                 // S0 u16; aliased f32 scratch
    __shared__ __align__(16) char es[FULL ? 65536 : 16];     // probs f16 (FULL only)

    int tid = threadIdx.x;
    int wv = tid >> 6;          // 0..15 = head (QK^T/premix-j) and output head (PV)
    int l  = tid & 63;
    int lr = l & 15;
    int lc = l >> 4;

    int bid   = blockIdx.x;
    int it2   = bid & 63;
    int b     = (bid >> 6) & 1;
    int split = bid >> 7;       // FULL: 0..1, else 0..3

    h4v wpre4;
    #pragma unroll
    for (int e = 0; e < 4; ++e) wpre4[e] = (f16)(Wpre[lr * 16 + lc * 4 + e] * (SCALE * LOG2E));
    h4v wpost;
    if (FULL) {
        #pragma unroll
        for (int e = 0; e < 4; ++e) wpost[e] = (f16)Wpost[lr * 16 + lc * 4 + e];
    }

    // Q fragments for head wv: [itile][ks]
    h8v qf[2][2];
    #pragma unroll
    for (int itl = 0; itl < 2; ++itl)
        #pragma unroll
        for (int ks = 0; ks < 2; ++ks) {
            size_t off = ((((size_t)((b*128 + it2*2 + itl)*16 + wv)*2 + ks)*4 + lc)*16 + lr)*8;
            qf[itl][ks] = *(const h8v*)(Qh + off);
        }

    f4v m4n[2];                 // -log2(Z) per (g'=lc*4+r, i=lr) as premix C-init
    if (FULL) {
        float* zrd = (float*)ss;
        if (tid < 512) {
            int itl = tid >> 8, g = (tid >> 4) & 15, i = tid & 15;
            size_t idx = (size_t)(b * 16 + g) * SEQ + it2 * 32 + itl * 16 + i;
            zrd[tid] = log2f(Zp[idx] + Zp[65536 + idx] + Zp[131072 + idx] + Zp[196608 + idx]);
        }
        __syncthreads();
        #pragma unroll
        for (int itl = 0; itl < 2; ++itl)
            #pragma unroll
            for (int r = 0; r < 4; ++r)
                m4n[itl][r] = -zrd[itl * 256 + (lc * 4 + r) * 16 + lr];
        __syncthreads();
    }

    f4v pv[2][4];
    if (FULL) {
        #pragma unroll
        for (int itl = 0; itl < 2; ++itl)
            #pragma unroll
            for (int dt = 0; dt < 4; ++dt) pv[itl][dt] = (f4v){0.f, 0.f, 0.f, 0.f};
    }
    float zacc[2][4] = {};

    const int NSTEP = FULL ? 16 : 8;
    int j0beg = split * (FULL ? 1024 : 512);
    int jtbeg = j0beg >> 4;
    int jvbeg = j0beg >> 5;

    // K burst loader: burst jsp covers jt = s*4 + jsp*2 + {0,1}
    auto ldK2 = [&](int s, int jsp, h8v (&kf)[2][2]) {
        #pragma unroll
        for (int js2 = 0; js2 < 2; ++js2)
            #pragma unroll
            for (int ks = 0; ks < 2; ++ks) {
                int jt = jtbeg + s * 4 + jsp * 2 + js2;
                size_t off = ((((size_t)((b*128 + jt)*16 + wv)*2 + ks)*4 + lc)*16 + lr)*8;
                kf[js2][ks] = *(const h8v*)(Kh + off);
            }
    };

    h8v kp[2][2];               // burst-0 (prefetched across steps when FULL)
    if (FULL) ldK2(0, 0, kp);

    for (int s = 0; s < NSTEP; ++s) {
        if (!FULL) ldK2(s, 0, kp);
        // V for jb=0 (consumed after 2 barriers)
        h8v vf0[4];
        if (FULL) {
            int jt32 = jvbeg + s * 2;
            #pragma unroll
            for (int dt = 0; dt < 4; ++dt) {
                size_t voff = (((((size_t)(b*64 + jt32)*16 + wv)*4 + dt)*4 + lc)*16 + lr)*8;
                vf0[dt] = *(const h8v*)(Vt + voff);
            }
        }
        // burst-1 K (in-step)
        h8v kf1[2][2];
        ldK2(s, 1, kf1);

        // QK^T: burst 0 (js 0,1) from kp, burst 1 (js 2,3) from kf1
        #pragma unroll
        for (int jsp = 0; jsp < 2; ++jsp) {
            #pragma unroll
            for (int itl = 0; itl < 2; ++itl)
                #pragma unroll
                for (int js2 = 0; js2 < 2; ++js2) {
                    const h8v* kk = jsp ? kf1[js2] : kp[js2];
                    f4v q = (f4v){0.f, 0.f, 0.f, 0.f};
                    q = mfma32(qf[itl][0], kk[0], q);
                    q = mfma32(qf[itl][1], kk[1], q);
                    int js = jsp * 2 + js2;
                    #pragma unroll
                    for (int r = 0; r < 4; ++r) {
                        int i = lc * 4 + r;
                        int addr = itl * 32768 + ((wv >> 2) * 4 + js) * 2048
                                 + i * 128 + ((lr ^ i) << 3) + (wv & 3) * 2;
                        *(u16*)(ss + addr) = __builtin_bit_cast(u16, (f16)q[r]);
                    }
                }
        }
        // prefetch next step's burst-0 (lands during premix+PV)
        if (FULL && s + 1 < NSTEP) ldK2(s + 1, 0, kp);
        __syncthreads();

        // premix (C = -log2 Z for FULL) -> exp2 -> (Z | postmix -> es)
        #pragma unroll
        for (int itl = 0; itl < 2; ++itl) {
            u32 a2p[4][2];
            #pragma unroll
            for (int tt = 0; tt < 4; ++tt) {
                int t = wv * 4 + tt;
                int addr = itl * 32768 + (lc * 4 + (t >> 4)) * 2048
                         + lr * 128 + (((t & 15) ^ lr) << 3);
                union { uint2 u; h4v v; } cv;
                cv.u = *(uint2*)(ss + addr);
                if (!FULL) {
                    f4v s1 = mfma16(wpre4, cv.v, (f4v){0.f, 0.f, 0.f, 0.f});
                    #pragma unroll
                    for (int r = 0; r < 4; ++r) zacc[itl][r] += fexp2(s1[r]);
                } else {
                    f4v s1 = mfma16(wpre4, cv.v, m4n[itl]);
                    h4v pf;
                    #pragma unroll
                    for (int r = 0; r < 4; ++r) pf[r] = (f16)fexp2(s1[r]);
                    f4v a2 = mfma16(wpost, pf, (f4v){0.f, 0.f, 0.f, 0.f});
                    #pragma unroll
                    for (int r = 0; r < 4; ++r) {
                        u32 v = (u32)__builtin_bit_cast(u16, (f16)a2[r]);
                        if (tt & 1) a2p[r][tt >> 1] |= v << 16;
                        else        a2p[r][tt >> 1]  = v;
                    }
                }
            }
            if (FULL) {
                #pragma unroll
                for (int r = 0; r < 4; ++r) {
                    int gq = lc * 4 + r;
                    int off = itl * 32768 + gq * 2048 + lr * 128
                            + ((wv * 8) ^ ((lr & 7) << 4));
                    *(uint2*)(es + off) = make_uint2(a2p[r][0], a2p[r][1]);
                }
            }
        }
        // V for jb=1 (consumed right after the barrier)
        h8v vf1[4];
        if (FULL) {
            int jt32 = jvbeg + s * 2 + 1;
            #pragma unroll
            for (int dt = 0; dt < 4; ++dt) {
                size_t voff = (((((size_t)(b*64 + jt32)*16 + wv)*4 + dt)*4 + lc)*16 + lr)*8;
                vf1[dt] = *(const h8v*)(Vt + voff);
            }
        }
        __syncthreads();

        // PV (output head wv): both j32-halves
        if (FULL) {
            #pragma unroll
            for (int itl = 0; itl < 2; ++itl) {
                h8v af0 = *(h8v*)(es + itl * 32768 + wv * 2048 + lr * 128
                                  + ((0 * 64 + lc * 16) ^ ((lr & 7) << 4)));
                h8v af1 = *(h8v*)(es + itl * 32768 + wv * 2048 + lr * 128
                                  + ((1 * 64 + lc * 16) ^ ((lr & 7) << 4)));
                #pragma unroll
                for (int dt = 0; dt < 4; ++dt)
                    pv[itl][dt] = mfma32(af0, vf0[dt], pv[itl][dt]);
                #pragma unroll
                for (int dt = 0; dt < 4; ++dt)
                    pv[itl][dt] = mfma32(af1, vf1[dt], pv[itl][dt]);
            }
        }
    }

    if (!FULL) {
        float* zrd = (float*)ss;   // ss dead after last premix (final barrier passed)
        #pragma unroll
        for (int itl = 0; itl < 2; ++itl)
            #pragma unroll
            for (int r = 0; r < 4; ++r)
                zrd[itl * 4096 + ((lc * 4 + r) * 16 + lr) * 16 + wv] = zacc[itl][r];
        __syncthreads();
        if (tid < 512) {
            int itl = tid >> 8, gi = tid & 255;
            float z = 0.f;
            #pragma unroll
            for (int w2 = 0; w2 < 16; ++w2) z += zrd[itl * 4096 + gi * 16 + w2];
            int g = gi >> 4, i = gi & 15;
            Zout[(size_t)split * 65536 + (size_t)(b * 16 + g) * SEQ + it2 * 32 + itl * 16 + i] = z;
        }
    } else {
        f16* dst = Octx + (size_t)split * 4194304;
        #pragma unroll
        for (int itl = 0; itl < 2; ++itl)
            #pragma unroll
            for (int dt = 0; dt < 4; ++dt)
                #pragma unroll
                for (int r = 0; r < 4; ++r) {
                    int row = it2 * 32 + itl * 16 + lc * 4 + r;
                    int col = wv * 64 + dt * 16 + lr;
                    dst[(size_t)(b * SEQ + row) * DMODEL + col] = (f16)pv[itl][dt][r];
                }
    }
}

// ---------------------------------------------------------------------------
extern "C" void kernel_launch(void* const* d_in, const int* in_sizes, int n_in,
                              void* d_out, int out_size, void* d_ws, size_t ws_size,
                              hipStream_t stream)
{
    const float* x     = (const float*)d_in[0];
    const float* Wqkv  = (const float*)d_in[1];
    const float* bqkv  = (const float*)d_in[2];
    const float* Wpre  = (const float*)d_in[3];
    const float* Wpost = (const float*)d_in[4];
    const float* Wout  = (const float*)d_in[5];
    const float* bout  = (const float*)d_in[6];
    float* out = (float*)d_out;

    float* ws = (float*)d_ws;
    f16*   QKVh = (f16*)(ws);                  // [0, 6.3M floats) f16; dead after packs
    f16*   CTXp = (f16*)(ws);                  // [0, 4M floats) 2 x f16 partials (overlay)
    f16*   Xh   = (f16*)(ws + 8388608);
    f16*   Wqh  = (f16*)(ws + 10485760);
    f16*   Woh  = (f16*)(ws + 12058624);
    f16*   Qh   = (f16*)(ws + 12582912);
    f16*   Kh   = (f16*)(ws + 14680064);
    f16*   Vt   = (f16*)(ws + 16777216);
    f16*   Ch   = (f16*)(ws + 18874368);
    float* Zp   = ws + 19922944;               // 4 x 65536 floats
    float2* Tab = (float2*)(ws + 20185088);    // 65536 float2 (rewritten every call)

    dim3 blk(256);
    rope_tab_kernel<<<256, blk, 0, stream>>>(Tab);
    cvt_f16_kernel<<<4096, blk, 0, stream>>>(x, Wqkv, Wout, Xh, Wqh, Woh);
    gemm_f16_kernel<<<dim3(24, 32), blk, 0, stream>>>(Xh, Wqh, bqkv, (void*)QKVh, 3072, 1024, 0);
    pack_qk_kernel<<<2048, blk, 0, stream>>>(QKVh, Tab, Qh, Kh);
    pack_v_kernel<<<2048, blk, 0, stream>>>(QKVh, Vt);
    attn_core<0><<<512, dim3(1024), 0, stream>>>(Qh, Kh, Vt, Wpre, Wpost, nullptr, Zp, nullptr);
    attn_core<1><<<256, dim3(1024), 0, stream>>>(Qh, Kh, Vt, Wpre, Wpost, Zp, nullptr, CTXp);
    pack_ctx_kernel<<<2048, blk, 0, stream>>>(CTXp, Ch);
    gemm_f16_kernel<<<dim3(8, 32), blk, 0, stream>>>(Ch, Woh, bout, (void*)out, 1024, 1024, 1);
}

// Round 16
// 202.456 us; speedup vs baseline: 1.3724x; 1.3724x over previous
//
#include <hip/hip_runtime.h>
#include <cstddef>
#include <cstdint>

#define SEQ    2048
#define DMODEL 1024
#define NHEAD  16
#define HDIM   64
#define SCALE  0.125f
#define LOG2E  1.4426950408889634f

typedef _Float16 f16;
typedef unsigned short u16;
typedef unsigned int   u32;
typedef __attribute__((ext_vector_type(8))) _Float16 h8v;
typedef __attribute__((ext_vector_type(4))) _Float16 h4v;
typedef __attribute__((ext_vector_type(4))) float    f4v;

__device__ __forceinline__ u32 pkh(float a, float b) {
    u16 x = __builtin_bit_cast(u16, (f16)a);
    u16 y = __builtin_bit_cast(u16, (f16)b);
    return (u32)x | ((u32)y << 16);
}

__device__ __forceinline__ float fexp2(float x) {
#if __has_builtin(__builtin_amdgcn_exp2f)
    return __builtin_amdgcn_exp2f(x);
#else
    return exp2f(x);
#endif
}

__device__ __forceinline__ f4v mfma32(h8v a, h8v b, f4v c) {
    return __builtin_amdgcn_mfma_f32_16x16x32_f16(a, b, c, 0, 0, 0);
}
__device__ __forceinline__ f4v mfma16(h4v a, h4v b, f4v c) {
    return __builtin_amdgcn_mfma_f32_16x16x16f16(a, b, c, 0, 0, 0);
}

// ---------------------------------------------------------------------------
// Prep: blocks 0..4095 convert x/Wqkv/Wout -> f16; blocks 4096..4351 build
// the RoPE table tab[pos*32+t] = (cos,sin)(pos / 10000^(2t/64)).
// ---------------------------------------------------------------------------
__global__ __launch_bounds__(256)
void prep_kernel(const float* __restrict__ x, const float* __restrict__ Wqkv,
                 const float* __restrict__ Wout,
                 f16* __restrict__ Xh, f16* __restrict__ Wqh, f16* __restrict__ Woh,
                 float2* __restrict__ tab)
{
    if (blockIdx.x >= 4096) {
        int gid = (blockIdx.x - 4096) * 256 + threadIdx.x;   // 65536
        int pos = gid >> 5, t = gid & 31;
        float inv = exp2f((float)(-2 * t) * (0.015625f * 13.287712379549449f));
        float c, s;
        sincosf((float)pos * inv, &s, &c);
        tab[gid] = make_float2(c, s);
        return;
    }
    size_t i = ((size_t)blockIdx.x * 256 + threadIdx.x) * 8;
    const float* src; f16* dst; size_t off;
    if (i < 4194304)      { src = x;    dst = Xh;  off = i; }
    else if (i < 7340032) { src = Wqkv; dst = Wqh; off = i - 4194304; }
    else                  { src = Wout; dst = Woh; off = i - 7340032; }
    float4 a = *(const float4*)&src[off];
    float4 b = *(const float4*)&src[off + 4];
    uint4 o;
    o.x = pkh(a.x, a.y); o.y = pkh(a.z, a.w);
    o.z = pkh(b.x, b.y); o.w = pkh(b.z, b.w);
    *(uint4*)&dst[off] = o;
}

// ---------------------------------------------------------------------------
// f16 MFMA GEMM: C = A @ B^T + bias. 128x128 tile, BK=32, 4 waves,
// reg-staged LDS with slot-XOR swizzle, next-tile register prefetch (r14).
// mode 0: store f16. mode 1: store fp32.
// ---------------------------------------------------------------------------
__global__ __launch_bounds__(256)
void gemm_f16_kernel(const f16* __restrict__ A, const f16* __restrict__ B,
                     const float* __restrict__ bias, void* __restrict__ Cout,
                     int N, int K, int mode)
{
    __shared__ __align__(16) char Asb[8192];
    __shared__ __align__(16) char Bsb[8192];
    int tid = threadIdx.x;
    int w = tid >> 6, l = tid & 63, lr = l & 15, lc = l >> 4;
    int row0 = blockIdx.y * 128, col0 = blockIdx.x * 128;
    int wr = (w >> 1) * 64, wc = (w & 1) * 64;

    f4v acc[4][4];
    #pragma unroll
    for (int m = 0; m < 4; ++m)
        #pragma unroll
        for (int n = 0; n < 4; ++n) acc[m][n] = (f4v){0.f, 0.f, 0.f, 0.f};

    int r0 = tid >> 2, k0s = tid & 3;
    int r1 = (tid + 256) >> 2, k1s = tid & 3;

    uint4 ra0, ra1, rb0, rb1;
    ra0 = *(const uint4*)&A[(size_t)(row0 + r0) * K + k0s * 8];
    ra1 = *(const uint4*)&A[(size_t)(row0 + r1) * K + k1s * 8];
    rb0 = *(const uint4*)&B[(size_t)(col0 + r0) * K + k0s * 8];
    rb1 = *(const uint4*)&B[(size_t)(col0 + r1) * K + k1s * 8];

    int NT = K >> 5;
    for (int kt = 0; kt < NT; ++kt) {
        *(uint4*)(Asb + r0 * 64 + ((k0s ^ (r0 & 3)) << 4)) = ra0;
        *(uint4*)(Asb + r1 * 64 + ((k1s ^ (r1 & 3)) << 4)) = ra1;
        *(uint4*)(Bsb + r0 * 64 + ((k0s ^ (r0 & 3)) << 4)) = rb0;
        *(uint4*)(Bsb + r1 * 64 + ((k1s ^ (r1 & 3)) << 4)) = rb1;
        if (kt + 1 < NT) {
            int kk = (kt + 1) * 32;
            ra0 = *(const uint4*)&A[(size_t)(row0 + r0) * K + kk + k0s * 8];
            ra1 = *(const uint4*)&A[(size_t)(row0 + r1) * K + kk + k1s * 8];
            rb0 = *(const uint4*)&B[(size_t)(col0 + r0) * K + kk + k0s * 8];
            rb1 = *(const uint4*)&B[(size_t)(col0 + r1) * K + kk + k1s * 8];
        }
        __syncthreads();
        h8v af[4], bf[4];
        #pragma unroll
        for (int m = 0; m < 4; ++m) {
            int row = wr + m * 16 + lr;
            af[m] = *(h8v*)(Asb + row * 64 + ((lc ^ (row & 3)) << 4));
        }
        #pragma unroll
        for (int n = 0; n < 4; ++n) {
            int col = wc + n * 16 + lr;
            bf[n] = *(h8v*)(Bsb + col * 64 + ((lc ^ (col & 3)) << 4));
        }
        #pragma unroll
        for (int m = 0; m < 4; ++m)
            #pragma unroll
            for (int n = 0; n < 4; ++n)
                acc[m][n] = mfma32(af[m], bf[n], acc[m][n]);
        __syncthreads();
    }

    #pragma unroll
    for (int m = 0; m < 4; ++m)
        #pragma unroll
        for (int r = 0; r < 4; ++r) {
            int row = row0 + wr + m * 16 + lc * 4 + r;
            #pragma unroll
            for (int n = 0; n < 4; ++n) {
                int col = col0 + wc + n * 16 + lr;
                float v = acc[m][n][r] + bias[col];
                if (mode == 0) ((f16*)Cout)[(size_t)row * N + col] = (f16)v;
                else           ((float*)Cout)[(size_t)row * N + col] = v;
            }
        }
}

// ---------------------------------------------------------------------------
// Pack Q,K (RoPE via table) and V from f16 QKV [row][3072] into frag layouts.
// Blocks 0..2047: QK. Blocks 2048..4095: V.
// ---------------------------------------------------------------------------
__global__ __launch_bounds__(256)
void pack_qkv_kernel(const f16* __restrict__ QKVh, const float2* __restrict__ tab,
                     f16* __restrict__ Qh, f16* __restrict__ Kh, f16* __restrict__ Vt)
{
    if (blockIdx.x >= 2048) {
        int gid = (blockIdx.x - 2048) * 256 + threadIdx.x;
        int dd = gid & 15;
        int jc = (gid >> 4) & 3;
        int dt = (gid >> 6) & 3;
        int g  = (gid >> 8) & 15;
        int jt = (gid >> 12) & 63;
        int b  = (gid >> 18) & 1;
        int d = g * 64 + dt * 16 + dd;
        f16 v[8];
        #pragma unroll
        for (int e = 0; e < 8; ++e) {
            int j = jt * 32 + jc * 8 + e;
            v[e] = QKVh[(size_t)(b * SEQ + j) * 3072 + 2048 + d];
        }
        size_t off = ((((((size_t)b*64 + jt)*16 + g)*4 + dt)*4 + jc)*16 + dd)*8;
        uint4 o;
        o.x = pkh((float)v[0], (float)v[1]); o.y = pkh((float)v[2], (float)v[3]);
        o.z = pkh((float)v[4], (float)v[5]); o.w = pkh((float)v[6], (float)v[7]);
        *(uint4*)(Vt + off) = o;
        return;
    }
    int gid = blockIdx.x * 256 + threadIdx.x;
    int i     = gid & 15;
    int t8    = (gid >> 4) & 3;
    int h     = (gid >> 6) & 15;
    int rh    = (gid >> 10) & 255;
    int which = (gid >> 18) & 1;
    int row = rh * 16 + i;
    int pos = row & (SEQ - 1);
    int b   = row >> 11;
    f16* dst = which ? Kh : Qh;

    h8v x1 = *(const h8v*)&QKVh[(size_t)row * 3072 + which * 1024 + h * 64 + t8 * 8];
    h8v x2 = *(const h8v*)&QKVh[(size_t)row * 3072 + which * 1024 + h * 64 + t8 * 8 + 32];

    float y1[8], y2[8];
    #pragma unroll
    for (int e = 0; e < 8; ++e) {
        int t = t8 * 8 + e;
        float2 cs = tab[pos * 32 + t];
        float a1 = (float)x1[e], a2 = (float)x2[e];
        y1[e] = a1 * cs.x - a2 * cs.y;
        y2[e] = a1 * cs.y + a2 * cs.x;
    }
    int it = pos >> 4;
    size_t b0 = (((((size_t)(b*128 + it)*16 + h)*2 + 0)*4 + t8)*16 + i)*8;
    size_t b1 = (((((size_t)(b*128 + it)*16 + h)*2 + 1)*4 + t8)*16 + i)*8;
    uint4 o0, o1;
    o0.x = pkh(y1[0], y1[1]); o0.y = pkh(y1[2], y1[3]);
    o0.z = pkh(y1[4], y1[5]); o0.w = pkh(y1[6], y1[7]);
    o1.x = pkh(y2[0], y2[1]); o1.y = pkh(y2[2], y2[3]);
    o1.z = pkh(y2[4], y2[5]); o1.w = pkh(y2[6], y2[7]);
    *(uint4*)(dst + b0) = o0;
    *(uint4*)(dst + b1) = o1;
}

// ---------------------------------------------------------------------------
// Sum 2 f16 attention split partials -> f16 CTX [4096][1024]. Grid 2048.
// ---------------------------------------------------------------------------
__global__ __launch_bounds__(256)
void pack_ctx_kernel(const f16* __restrict__ Cp, f16* __restrict__ Ch)
{
    size_t i = ((size_t)blockIdx.x * 256 + threadIdx.x) * 8;
    h8v p0 = *(const h8v*)&Cp[i];
    h8v p1 = *(const h8v*)&Cp[i + 4194304];
    float s[8];
    #pragma unroll
    for (int e = 0; e < 8; ++e)
        s[e] = (float)p0[e] + (float)p1[e];
    uint4 o;
    o.x = pkh(s[0], s[1]); o.y = pkh(s[2], s[3]);
    o.z = pkh(s[4], s[5]); o.w = pkh(s[6], s[7]);
    *(uint4*)&Ch[i] = o;
}

// ---------------------------------------------------------------------------
// Two-pass MFMA talking-heads attention (r14-proven). 1024 threads = 16 waves,
// 1 head/wave. QBLK=32, j-step=64.
// FULL=0: 4 splits of 512 (grid 512, 2 blocks/CU, LDS 64KB) -> Z partials.
// FULL=1: 2 splits of 1024 (grid 256, LDS 131KB) -> CTX partials;
//         log2(Z) folded into premix MFMA C-operand. NO cross-step K prefetch
//         (r15: spills at the 64-VGPR floor -> 3.7x FETCH).
// ---------------------------------------------------------------------------
template<int FULL>
__global__ __launch_bounds__(1024, FULL ? 1 : 2)
void attn_core(const f16* __restrict__ Qh, const f16* __restrict__ Kh,
               const f16* __restrict__ Vt, const float* __restrict__ Wpre,
               const float* __restrict__ Wpost, const float* __restrict__ Zp,
               float* __restrict__ Zout, f16* __restrict__ Octx)
{
    __shared__ __align__(16) char ss[65536];                 // S0 u16; aliased f32 scratch
    __shared__ __align__(16) char es[FULL ? 65536 : 16];     // probs f16 (FULL only)

    int tid = threadIdx.x;
    int wv = tid >> 6;
    int l  = tid & 63;
    int lr = l & 15;
    int lc = l >> 4;

    int bid   = blockIdx.x;
    int it2   = bid & 63;
    int b     = (bid >> 6) & 1;
    int split = bid >> 7;

    h4v wpre4;
    #pragma unroll
    for (int e = 0; e < 4; ++e) wpre4[e] = (f16)(Wpre[lr * 16 + lc * 4 + e] * (SCALE * LOG2E));
    h4v wpost;
    if (FULL) {
        #pragma unroll
        for (int e = 0; e < 4; ++e) wpost[e] = (f16)Wpost[lr * 16 + lc * 4 + e];
    }

    h8v qf[2][2];
    #pragma unroll
    for (int itl = 0; itl < 2; ++itl)
        #pragma unroll
        for (int ks = 0; ks < 2; ++ks) {
            size_t off = ((((size_t)((b*128 + it2*2 + itl)*16 + wv)*2 + ks)*4 + lc)*16 + lr)*8;
            qf[itl][ks] = *(const h8v*)(Qh + off);
        }

    f4v m4n[2];
    if (FULL) {
        float* zrd = (float*)ss;
        if (tid < 512) {
            int itl = tid >> 8, g = (tid >> 4) & 15, i = tid & 15;
            size_t idx = (size_t)(b * 16 + g) * SEQ + it2 * 32 + itl * 16 + i;
            zrd[tid] = log2f(Zp[idx] + Zp[65536 + idx] + Zp[131072 + idx] + Zp[196608 + idx]);
        }
        __syncthreads();
        #pragma unroll
        for (int itl = 0; itl < 2; ++itl)
            #pragma unroll
            for (int r = 0; r < 4; ++r)
                m4n[itl][r] = -zrd[itl * 256 + (lc * 4 + r) * 16 + lr];
        __syncthreads();
    }

    f4v pv[2][4];
    if (FULL) {
        #pragma unroll
        for (int itl = 0; itl < 2; ++itl)
            #pragma unroll
            for (int dt = 0; dt < 4; ++dt) pv[itl][dt] = (f4v){0.f, 0.f, 0.f, 0.f};
    }
    float zacc[2][4] = {};

    const int NSTEP = FULL ? 16 : 8;
    int j0beg = split * (FULL ? 1024 : 512);
    int jtbeg = j0beg >> 4;
    int jvbeg = j0beg >> 5;

    for (int s = 0; s < NSTEP; ++s) {
        h8v vf0[4];
        if (FULL) {
            int jt32 = jvbeg + s * 2;
            #pragma unroll
            for (int dt = 0; dt < 4; ++dt) {
                size_t voff = (((((size_t)(b*64 + jt32)*16 + wv)*4 + dt)*4 + lc)*16 + lr)*8;
                vf0[dt] = *(const h8v*)(Vt + voff);
            }
        }
        #pragma unroll
        for (int jsp = 0; jsp < 2; ++jsp) {
            h8v kf[2][2];
            #pragma unroll
            for (int js2 = 0; js2 < 2; ++js2)
                #pragma unroll
                for (int ks = 0; ks < 2; ++ks) {
                    int jt = jtbeg + s * 4 + jsp * 2 + js2;
                    size_t off = ((((size_t)((b*128 + jt)*16 + wv)*2 + ks)*4 + lc)*16 + lr)*8;
                    kf[js2][ks] = *(const h8v*)(Kh + off);
                }
            #pragma unroll
            for (int itl = 0; itl < 2; ++itl)
                #pragma unroll
                for (int js2 = 0; js2 < 2; ++js2) {
                    f4v q = (f4v){0.f, 0.f, 0.f, 0.f};
                    q = mfma32(qf[itl][0], kf[js2][0], q);
                    q = mfma32(qf[itl][1], kf[js2][1], q);
                    int js = jsp * 2 + js2;
                    #pragma unroll
                    for (int r = 0; r < 4; ++r) {
                        int i = lc * 4 + r;
                        int addr = itl * 32768 + ((wv >> 2) * 4 + js) * 2048
                                 + i * 128 + ((lr ^ i) << 3) + (wv & 3) * 2;
                        *(u16*)(ss + addr) = __builtin_bit_cast(u16, (f16)q[r]);
                    }
                }
        }
        __syncthreads();

        #pragma unroll
        for (int itl = 0; itl < 2; ++itl) {
            u32 a2p[4][2];
            #pragma unroll
            for (int tt = 0; tt < 4; ++tt) {
                int t = wv * 4 + tt;
                int addr = itl * 32768 + (lc * 4 + (t >> 4)) * 2048
                         + lr * 128 + (((t & 15) ^ lr) << 3);
                union { uint2 u; h4v v; } cv;
                cv.u = *(uint2*)(ss + addr);
                if (!FULL) {
                    f4v s1 = mfma16(wpre4, cv.v, (f4v){0.f, 0.f, 0.f, 0.f});
                    #pragma unroll
                    for (int r = 0; r < 4; ++r) zacc[itl][r] += fexp2(s1[r]);
                } else {
                    f4v s1 = mfma16(wpre4, cv.v, m4n[itl]);
                    h4v pf;
                    #pragma unroll
                    for (int r = 0; r < 4; ++r) pf[r] = (f16)fexp2(s1[r]);
                    f4v a2 = mfma16(wpost, pf, (f4v){0.f, 0.f, 0.f, 0.f});
                    #pragma unroll
                    for (int r = 0; r < 4; ++r) {
                        u32 v = (u32)__builtin_bit_cast(u16, (f16)a2[r]);
                        if (tt & 1) a2p[r][tt >> 1] |= v << 16;
                        else        a2p[r][tt >> 1]  = v;
                    }
                }
            }
            if (FULL) {
                #pragma unroll
                for (int r = 0; r < 4; ++r) {
                    int gq = lc * 4 + r;
                    int off = itl * 32768 + gq * 2048 + lr * 128
                            + ((wv * 8) ^ ((lr & 7) << 4));
                    *(uint2*)(es + off) = make_uint2(a2p[r][0], a2p[r][1]);
                }
            }
        }
        h8v vf1[4];
        if (FULL) {
            int jt32 = jvbeg + s * 2 + 1;
            #pragma unroll
            for (int dt = 0; dt < 4; ++dt) {
                size_t voff = (((((size_t)(b*64 + jt32)*16 + wv)*4 + dt)*4 + lc)*16 + lr)*8;
                vf1[dt] = *(const h8v*)(Vt + voff);
            }
        }
        __syncthreads();

        if (FULL) {
            #pragma unroll
            for (int itl = 0; itl < 2; ++itl) {
                h8v af0 = *(h8v*)(es + itl * 32768 + wv * 2048 + lr * 128
                                  + ((0 * 64 + lc * 16) ^ ((lr & 7) << 4)));
                h8v af1 = *(h8v*)(es + itl * 32768 + wv * 2048 + lr * 128
                                  + ((1 * 64 + lc * 16) ^ ((lr & 7) << 4)));
                #pragma unroll
                for (int dt = 0; dt < 4; ++dt)
                    pv[itl][dt] = mfma32(af0, vf0[dt], pv[itl][dt]);
                #pragma unroll
                for (int dt = 0; dt < 4; ++dt)
                    pv[itl][dt] = mfma32(af1, vf1[dt], pv[itl][dt]);
            }
        }
    }

    if (!FULL) {
        float* zrd = (float*)ss;
        #pragma unroll
        for (int itl = 0; itl < 2; ++itl)
            #pragma unroll
            for (int r = 0; r < 4; ++r)
                zrd[itl * 4096 + ((lc * 4 + r) * 16 + lr) * 16 + wv] = zacc[itl][r];
        __syncthreads();
        if (tid < 512) {
            int itl = tid >> 8, gi = tid & 255;
            float z = 0.f;
            #pragma unroll
            for (int w2 = 0; w2 < 16; ++w2) z += zrd[itl * 4096 + gi * 16 + w2];
            int g = gi >> 4, i = gi & 15;
            Zout[(size_t)split * 65536 + (size_t)(b * 16 + g) * SEQ + it2 * 32 + itl * 16 + i] = z;
        }
    } else {
        f16* dst = Octx + (size_t)split * 4194304;
        #pragma unroll
        for (int itl = 0; itl < 2; ++itl)
            #pragma unroll
            for (int dt = 0; dt < 4; ++dt)
                #pragma unroll
                for (int r = 0; r < 4; ++r) {
                    int row = it2 * 32 + itl * 16 + lc * 4 + r;
                    int col = wv * 64 + dt * 16 + lr;
                    dst[(size_t)(b * SEQ + row) * DMODEL + col] = (f16)pv[itl][dt][r];
                }
    }
}

// ---------------------------------------------------------------------------
extern "C" void kernel_launch(void* const* d_in, const int* in_sizes, int n_in,
                              void* d_out, int out_size, void* d_ws, size_t ws_size,
                              hipStream_t stream)
{
    const float* x     = (const float*)d_in[0];
    const float* Wqkv  = (const float*)d_in[1];
    const float* bqkv  = (const float*)d_in[2];
    const float* Wpre  = (const float*)d_in[3];
    const float* Wpost = (const float*)d_in[4];
    const float* Wout  = (const float*)d_in[5];
    const float* bout  = (const float*)d_in[6];
    float* out = (float*)d_out;

    float* ws = (float*)d_ws;
    f16*   QKVh = (f16*)(ws);                  // [0, 6.3M floats) f16; dead after packs
    f16*   CTXp = (f16*)(ws);                  // [0, 4M floats) 2 x f16 partials (overlay)
    f16*   Xh   = (f16*)(ws + 8388608);
    f16*   Wqh  = (f16*)(ws + 10485760);
    f16*   Woh  = (f16*)(ws + 12058624);
    f16*   Qh   = (f16*)(ws + 12582912);
    f16*   Kh   = (f16*)(ws + 14680064);
    f16*   Vt   = (f16*)(ws + 16777216);
    f16*   Ch   = (f16*)(ws + 18874368);
    float* Zp   = ws + 19922944;               // 4 x 65536 floats
    float2* Tab = (float2*)(ws + 20185088);    // 65536 float2 (rewritten every call)

    dim3 blk(256);
    prep_kernel<<<4352, blk, 0, stream>>>(x, Wqkv, Wout, Xh, Wqh, Woh, Tab);
    gemm_f16_kernel<<<dim3(24, 32), blk, 0, stream>>>(Xh, Wqh, bqkv, (void*)QKVh, 3072, 1024, 0);
    pack_qkv_kernel<<<4096, blk, 0, stream>>>(QKVh, Tab, Qh, Kh, Vt);
    attn_core<0><<<512, dim3(1024), 0, stream>>>(Qh, Kh, Vt, Wpre, Wpost, nullptr, Zp, nullptr);
    attn_core<1><<<256, dim3(1024), 0, stream>>>(Qh, Kh, Vt, Wpre, Wpost, Zp, nullptr, CTXp);
    pack_ctx_kernel<<<2048, blk, 0, stream>>>(CTXp, Ch);
    gemm_f16_kernel<<<dim3(8, 32), blk, 0, stream>>>(Ch, Woh, bout, (void*)out, 1024, 1024, 1);
}